// Round 5
// baseline (162.715 us; speedup 1.0000x reference)
//
#include <hip/hip_runtime.h>
#include <stdint.h>

// CRF loss: A=8, S=200, B=64, T=32. scores (A,S,B,T,T) f32, targets (A,S,B) i32,
// mask (S,B) bool, a_mask (A,B) bool -- bool width (u8 vs i32) runtime-detected.
// One wave per (a,b) chain. Linear-domain forward recursion (R4 math, absmax 0).
// NEW: deep async pipeline -- global_load_lds (16B/lane) into a 14-slot LDS tile
// ring, counted s_waitcnt vmcnt(48) (12 tiles may stay in flight), so 13 tiles
// = 52 KB/wave are outstanding vs 13 KB before (vmcnt-cap-limited scalar loads).
constexpr int A_ = 8, S_ = 200, B_ = 64, T_ = 32;
constexpr int START_TAG = 30, END_TAG = 31;
constexpr int NBUF = 14;                  // LDS ring slots (4 KB each)
#define LOG2E 1.44269504088896340736f
#define LN2   0.69314718055994530942f

#if __has_builtin(__builtin_amdgcn_exp2f)
#define EXP2F(x) __builtin_amdgcn_exp2f(x)
#else
#define EXP2F(x) __expf((x) * LN2)
#endif

typedef const void __attribute__((address_space(1)))* gas_ptr;
typedef void __attribute__((address_space(3)))* las_ptr;

__device__ __forceinline__ int load_flag(const void* p, bool u8, int idx) {
    return u8 ? (int)((const unsigned char*)p)[idx] : ((const int*)p)[idx];
}

__global__ __launch_bounds__(64)
void crf_loss_kernel(const float* __restrict__ scores,
                     const int* __restrict__ targets,
                     const void* __restrict__ mask,
                     const void* __restrict__ amask,
                     float* __restrict__ out)
{
    const int chain = blockIdx.x;          // 0..511
    const int a = chain >> 6;
    const int b = chain & (B_ - 1);
    const int lane = threadIdx.x;          // 0..63
    const int t = lane & 31;
    const int fbase = (lane >> 5) << 4;    // 0 or 16

    // bool width detect: mask row 0 is all-true. int view: 1 -> int32, 0x01010101 -> uint8
    const bool bool_u8 = (((const int*)mask)[0] != 1);
    if (!load_flag(amask, bool_u8, a * B_ + b)) return;

    __shared__ __align__(16) float ring[NBUF * 1024];   // 14 x 4 KB tiles
    __shared__ int tg_lds[S_];
    __shared__ __align__(16) float wlds[T_];

    // ---- first false mask index L (prefix mask; lengths in [100,200] so L>=100) ----
    int L = S_;
    for (int base = 0; base < S_; base += 64) {
        int i = base + lane;
        int mv = (i < S_) ? load_flag(mask, bool_u8, i * B_ + b) : 1;
        unsigned long long bal = __ballot(mv == 0);
        if (bal != 0ull && L == S_) L = base + (int)__builtin_ctzll(bal);
    }
    const int Lm1 = L - 1;

    for (int i = lane; i < S_; i += 64)
        tg_lds[i] = targets[((size_t)a * S_ + i) * B_ + b];

    const size_t s_stride = (size_t)B_ * T_ * T_;       // 65536 floats per s-step
    const float* cb = scores + ((size_t)a * S_ * B_ + b) * (T_ * T_);

    // Issue one 4 KB tile (tile SC) into ring slot SLOT: 4 x global_load_lds
    // (16 B/lane, LDS dest = uniform base + lane*16 -> exact row-major layout).
#define ISSUE(SLOT, SC) do {                                             \
        const float* gp_ = cb + (size_t)(SC) * s_stride;                 \
        char* lp_ = (char*)ring + (SLOT) * 4096;                         \
        _Pragma("unroll")                                                \
        for (int j_ = 0; j_ < 4; ++j_)                                   \
            __builtin_amdgcn_global_load_lds(                            \
                (gas_ptr)(gp_ + j_ * 256 + lane * 4),                    \
                (las_ptr)(lp_ + (j_ << 10)), 16, 0, 0);                  \
    } while (0)

    // ---- step 0: w[t] = exp(scores[a,0,b,START,t]);  gold energy from global ----
    float wcur = EXP2F(cb[START_TAG * T_ + t] * LOG2E);
    if (lane < 32) wlds[lane] = wcur;
    float C2 = 0.0f;                        // accumulated log2 offset (wave-uniform)
    float tg = (L > 0) ? cb[tg_lds[0]] : 0.0f;

    // ---- prologue: tiles 1..NBUF-1 into slots 1..NBUF-1 ----
    for (int p = 1; p < NBUF; ++p) {
        int pf = (p > Lm1) ? Lm1 : p;
        ISSUE(p, pf);
    }

    // One step from LDS slot CSL (tile SC): 16 conflict-free row reads + gather.
#define STEP(CSL, SC) do {                                               \
        const char* tb_ = (const char*)ring + (CSL) * 4096;              \
        int gi_ = tg_lds[SC];                                            \
        float4 wa_ = *(const float4*)&wlds[fbase];                       \
        float4 wb_ = *(const float4*)&wlds[fbase + 4];                   \
        float4 wc_ = *(const float4*)&wlds[fbase + 8];                   \
        float4 wd_ = *(const float4*)&wlds[fbase + 12];                  \
        float e_[16];                                                    \
        _Pragma("unroll")                                                \
        for (int i_ = 0; i_ < 16; ++i_)                                  \
            e_[i_] = EXP2F(*(const float*)(tb_ + ((fbase + i_) << 7)     \
                                           + (t << 2)) * LOG2E);         \
        float g_ = *(const float*)(tb_ + (gi_ << 2));                    \
        float s0_ = fmaf(e_[3], wa_.w, fmaf(e_[2], wa_.z,                \
                    fmaf(e_[1], wa_.y, e_[0] * wa_.x)));                 \
        float s1_ = fmaf(e_[7], wb_.w, fmaf(e_[6], wb_.z,                \
                    fmaf(e_[5], wb_.y, e_[4] * wb_.x)));                 \
        float s2_ = fmaf(e_[11], wc_.w, fmaf(e_[10], wc_.z,              \
                    fmaf(e_[9], wc_.y, e_[8] * wc_.x)));                 \
        float s3_ = fmaf(e_[15], wd_.w, fmaf(e_[14], wd_.z,              \
                    fmaf(e_[13], wd_.y, e_[12] * wd_.x)));               \
        float s_ = (s0_ + s1_) + (s2_ + s3_);                            \
        s_ += __shfl_xor(s_, 32);                                        \
        wcur = s_;                                                       \
        if (lane < 32) wlds[lane] = s_;                                  \
        tg += g_;                                                        \
    } while (0)

    // Exponent renorm (exact power of 2), every 4 steps (verified cadence, R4).
#define RENORM do {                                                      \
        float m_ = wcur;                                                 \
        m_ = fmaxf(m_, __shfl_xor(m_, 1));                               \
        m_ = fmaxf(m_, __shfl_xor(m_, 2));                               \
        m_ = fmaxf(m_, __shfl_xor(m_, 4));                               \
        m_ = fmaxf(m_, __shfl_xor(m_, 8));                               \
        m_ = fmaxf(m_, __shfl_xor(m_, 16));                              \
        int eb_ = (__float_as_int(m_) >> 23) & 0xff;                     \
        C2 += (float)(eb_ - 127);                                        \
        float sc2_ = __int_as_float((254 - eb_) << 23);                  \
        wcur *= sc2_;                                                    \
        if (lane < 32) wlds[lane] = wcur;                                \
    } while (0)

    // ---- main scan: wait tile s (counted, never 0), consume, issue tile s+13 ----
    static_assert(NBUF == 14, "vmcnt literal below assumes NBUF==14");
    int csl = 1;                            // slot of tile s
    int isl = 0;                            // slot for tile s+NBUF-1  (= (s-1)%NBUF)
    for (int s = 1; s < L; ++s) {
        int pf = s + (NBUF - 1); if (pf > Lm1) pf = Lm1;
        // allow 12 tiles (48 loads) outstanding -> oldest tile (s) has landed
        asm volatile("s_waitcnt vmcnt(48)" ::: "memory");
        __builtin_amdgcn_sched_barrier(0);
        STEP(csl, s);
        ISSUE(isl, pf);                     // exactly 4 VMEM ops every iter
        if ((s & 3) == 0) RENORM;
        if (++csl == NBUF) csl = 0;
        if (++isl == NBUF) isl = 0;
    }

    // ---- epilogue: logZ = ln(w[END_TAG]) + C2*ln2 ----
    float wend = __shfl(wcur, END_TAG);
    float logZ = __logf(wend) + C2 * LN2;
    if (lane == 0)
        atomicAdd(out, (logZ - tg) * (1.0f / (float)B_));
}

extern "C" void kernel_launch(void* const* d_in, const int* in_sizes, int n_in,
                              void* d_out, int out_size, void* d_ws, size_t ws_size,
                              hipStream_t stream) {
    const float* scores = (const float*)d_in[0];
    const int* targets  = (const int*)d_in[1];
    const void* mask    = d_in[2];
    const void* amask   = d_in[3];
    float* out = (float*)d_out;

    hipMemsetAsync(out, 0, sizeof(float), stream);
    crf_loss_kernel<<<dim3(A_ * B_), dim3(64), 0, stream>>>(
        scores, targets, mask, amask, out);
}

// Round 6
// 83.386 us; speedup vs baseline: 1.9513x; 1.9513x over previous
//
#include <hip/hip_runtime.h>

// CRF loss: A=8, S=200, B=64, T=32. scores (A,S,B,T,T) f32, targets (A,S,B) i32,
// mask (S,B) bool, a_mask (A,B) bool -- bool width (u8 vs i32) runtime-detected.
// One 8-wave block per (a,b) chain. Producer/consumer: each super-iteration,
// 8 waves load+exp one 4KB tile each into a double-buffered LDS ring; wave 0
// then runs 8 serial recursion steps (R4's linear-domain math, absmax 0) from
// LDS while producers prefetch the next 8 tiles into registers. TLP (16
// waves/CU) supplies the in-flight bytes single-wave ILP could not.
constexpr int A_ = 8, S_ = 200, B_ = 64, T_ = 32;
constexpr int START_TAG = 30, END_TAG = 31;
constexpr int NW = 8;                      // waves per block = tiles per super-iter
#define LOG2E 1.44269504088896340736f
#define LN2   0.69314718055994530942f

#if __has_builtin(__builtin_amdgcn_exp2f)
#define EXP2F(x) __builtin_amdgcn_exp2f(x)
#else
#define EXP2F(x) __expf((x) * LN2)
#endif

__device__ __forceinline__ int load_flag(const void* p, bool u8, int idx) {
    return u8 ? (int)((const unsigned char*)p)[idx] : ((const int*)p)[idx];
}

__global__ __launch_bounds__(NW * 64)
void crf_loss_kernel(const float* __restrict__ scores,
                     const int* __restrict__ targets,
                     const void* __restrict__ mask,
                     const void* __restrict__ amask,
                     float* __restrict__ out)
{
    const int chain = blockIdx.x;          // 0..511
    const int a = chain >> 6;
    const int b = chain & (B_ - 1);
    const int tid = threadIdx.x;
    const int wv = tid >> 6;               // wave 0..7
    const int lane = tid & 63;
    const int t = lane & 31;
    const int fbase = (lane >> 5) << 4;    // 0 or 16

    // bool width detect: mask row 0 is all-true. int view: 1 -> int32, 0x01010101 -> uint8
    const bool bool_u8 = (((const int*)mask)[0] != 1);
    if (!load_flag(amask, bool_u8, a * B_ + b)) return;   // uniform: whole block exits

    __shared__ __align__(16) float ebuf[2][NW][T_ * T_];  // 2 x 8 x 4KB = 64KB exp-tiles
    __shared__ float gside[2][NW];                        // raw gold-path scores
    __shared__ int tg_lds[S_];
    __shared__ __align__(16) float wlds[T_];              // partition vector (wave 0 only)

    // ---- first false mask index L (prefix mask), per-wave ballot ----
    int L = S_;
    for (int base = 0; base < S_; base += 64) {
        int i = base + lane;
        int mv = (i < S_) ? load_flag(mask, bool_u8, i * B_ + b) : 1;
        unsigned long long bal = __ballot(mv == 0);
        if (bal != 0ull && L == S_) L = base + (int)__builtin_ctzll(bal);
    }

    for (int i = tid; i < S_; i += NW * 64)
        tg_lds[i] = targets[((size_t)a * S_ + i) * B_ + b];
    __syncthreads();                        // tg_lds ready for producer gathers

    const size_t s_stride = (size_t)B_ * T_ * T_;         // 65536 floats per s-step
    const float* cb = scores + ((size_t)a * S_ * B_ + b) * (T_ * T_);

    // ---- wave 0 init: w[t] = exp(scores[a,0,b,START,t]); gold energy step 0 ----
    float wcur = 0.0f, C2 = 0.0f, tg = 0.0f;
    if (wv == 0) {
        wcur = EXP2F(cb[START_TAG * T_ + t] * LOG2E);
        if (lane < 32) wlds[lane] = wcur;
        tg = (L > 0) ? cb[tg_lds[0]] : 0.0f;
    }

    const int nch = (L - 1 + NW - 1) / NW;  // super-iterations (block-uniform)

#define E4(DST, SRC) do {                                                \
        DST.x = EXP2F(SRC.x * LOG2E); DST.y = EXP2F(SRC.y * LOG2E);      \
        DST.z = EXP2F(SRC.z * LOG2E); DST.w = EXP2F(SRC.w * LOG2E);      \
    } while (0)

#define RENORM do {                                                      \
        float m_ = wcur;                                                 \
        m_ = fmaxf(m_, __shfl_xor(m_, 1));                               \
        m_ = fmaxf(m_, __shfl_xor(m_, 2));                               \
        m_ = fmaxf(m_, __shfl_xor(m_, 4));                               \
        m_ = fmaxf(m_, __shfl_xor(m_, 8));                               \
        m_ = fmaxf(m_, __shfl_xor(m_, 16));                              \
        int eb_ = (__float_as_int(m_) >> 23) & 0xff;                     \
        C2 += (float)(eb_ - 127);                                        \
        float sc2_ = __int_as_float((254 - eb_) << 23);                  \
        wcur *= sc2_;                                                    \
        if (lane < 32) wlds[lane] = wcur;                                \
    } while (0)

    // ---- producer prefetch of chunk-0 tile (s = 1 + wv) ----
    float4 q0, q1, q2, q3;
    float graw = 0.0f;
    {
        int s0 = 1 + wv;
        if (s0 < L) {
            const float*  p  = cb + (size_t)s0 * s_stride;
            const float4* p4 = (const float4*)p;
            q0 = p4[lane]; q1 = p4[64 + lane]; q2 = p4[128 + lane]; q3 = p4[192 + lane];
            graw = p[tg_lds[s0]];
        }
    }

    for (int k = 0; k < nch; ++k) {
        const int scur = 1 + k * NW + wv;
        const int snxt = scur + NW;

        // issue next chunk's loads first (independent of this chunk's work)
        float4 n0, n1, n2, n3;
        float ngraw = 0.0f;
        if (snxt < L) {
            const float*  p  = cb + (size_t)snxt * s_stride;
            const float4* p4 = (const float4*)p;
            n0 = p4[lane]; n1 = p4[64 + lane]; n2 = p4[128 + lane]; n3 = p4[192 + lane];
            ngraw = p[tg_lds[snxt]];
        }

        // exp-transform current tile into LDS ring
        if (scur < L) {
            float4* eb = (float4*)&ebuf[k & 1][wv][0];
            float4 e0, e1, e2, e3;
            E4(e0, q0); E4(e1, q1); E4(e2, q2); E4(e3, q3);
            eb[lane] = e0; eb[64 + lane] = e1; eb[128 + lane] = e2; eb[192 + lane] = e3;
            if (lane == 0) gside[k & 1][wv] = graw;
        }
        __syncthreads();                    // ring half (k&1) complete

        // consumer: 8 serial recursion steps from LDS
        if (wv == 0) {
            const int jmax = min(NW, L - 1 - k * NW);
            for (int j = 0; j < jmax; ++j) {
                const int s = 1 + k * NW + j;
                const float* eb = &ebuf[k & 1][j][0];
                float4 wa_ = *(const float4*)&wlds[fbase];
                float4 wb_ = *(const float4*)&wlds[fbase + 4];
                float4 wc_ = *(const float4*)&wlds[fbase + 8];
                float4 wd_ = *(const float4*)&wlds[fbase + 12];
                float e_[16];
#pragma unroll
                for (int i = 0; i < 16; ++i)
                    e_[i] = eb[((fbase + i) << 5) | t];
                float s0_ = fmaf(e_[3], wa_.w, fmaf(e_[2], wa_.z,
                            fmaf(e_[1], wa_.y, e_[0] * wa_.x)));
                float s1_ = fmaf(e_[7], wb_.w, fmaf(e_[6], wb_.z,
                            fmaf(e_[5], wb_.y, e_[4] * wb_.x)));
                float s2_ = fmaf(e_[11], wc_.w, fmaf(e_[10], wc_.z,
                            fmaf(e_[9], wc_.y, e_[8] * wc_.x)));
                float s3_ = fmaf(e_[15], wd_.w, fmaf(e_[14], wd_.z,
                            fmaf(e_[13], wd_.y, e_[12] * wd_.x)));
                float s_ = (s0_ + s1_) + (s2_ + s3_);
                s_ += __shfl_xor(s_, 32);
                wcur = s_;
                if (lane < 32) wlds[lane] = s_;
                tg += gside[k & 1][j];
                if ((s & 3) == 0) RENORM;
            }
        }

        // rotate prefetch registers
        q0 = n0; q1 = n1; q2 = n2; q3 = n3; graw = ngraw;
    }

    // ---- epilogue (wave 0): logZ = ln(w[END_TAG]) + C2*ln2 ----
    if (wv == 0) {
        float wend = __shfl(wcur, END_TAG);
        float logZ = __logf(wend) + C2 * LN2;
        if (lane == 0)
            atomicAdd(out, (logZ - tg) * (1.0f / (float)B_));
    }
}

extern "C" void kernel_launch(void* const* d_in, const int* in_sizes, int n_in,
                              void* d_out, int out_size, void* d_ws, size_t ws_size,
                              hipStream_t stream) {
    const float* scores = (const float*)d_in[0];
    const int* targets  = (const int*)d_in[1];
    const void* mask    = d_in[2];
    const void* amask   = d_in[3];
    float* out = (float*)d_out;

    hipMemsetAsync(out, 0, sizeof(float), stream);
    crf_loss_kernel<<<dim3(A_ * B_), dim3(NW * 64), 0, stream>>>(
        scores, targets, mask, amask, out);
}